// Round 1
// baseline (824.060 us; speedup 1.0000x reference)
//
#include <hip/hip_runtime.h>
#include <math.h>

// MSMOM: multi-scale soft morphological opening + BN/ReLU + 1x1 conv + BN/ReLU
// B=4, C=64, H=W=256, k=3, dilations 1..4, beta=15.

constexpr int B_ = 4, C_ = 64, H_ = 256, W_ = 256;
constexpr int HW = H_ * W_;
constexpr float BIGV = 10000.0f;
constexpr float EPSV = 1e-5f;
// u = K * t  where K = beta * log2(e); logsumexp(beta*t)/beta = C1*(max_u + log2(sum 2^(u-max_u)))
constexpr float KL2E = 21.64042561333445f;    // 15 * log2(e)
constexpr float C1   = 0.046209812037329684f; // ln(2) / 15

template<int D>
__global__ __launch_bounds__(256) void morph_open_kernel(
    const float* __restrict__ x, const float* __restrict__ we,
    const float* __restrict__ wd, const float* __restrict__ bng,
    const float* __restrict__ bnb, const float* __restrict__ bnm,
    const float* __restrict__ bnv, float* __restrict__ cat, int d)
{
    constexpr int XT = 32 + 4 * D;  // x tile incl. halo 2D each side
    constexpr int ET = 32 + 2 * D;  // erosion tile incl. halo D each side
    __shared__ float xs[XT * XT];
    __shared__ float es[ET * ET];

    const int tid = threadIdx.x;
    const int tileW = blockIdx.x & 7, tileH = blockIdx.x >> 3;
    const int c = blockIdx.y, b = blockIdx.z;
    const int h0 = tileH * 32, w0 = tileW * 32;

    const float* xc = x + (b * C_ + c) * HW;

    // stage x tile (+BIG padding outside image: erosion taps w - BIG underflow to 0)
    for (int idx = tid; idx < XT * XT; idx += 256) {
        int r = idx / XT, q = idx - r * XT;
        int gh = h0 - 2 * D + r, gw = w0 - 2 * D + q;
        float v = BIGV;
        if (gh >= 0 && gh < H_ && gw >= 0 && gw < W_) v = xc[gh * W_ + gw];
        xs[idx] = v;
    }

    const float* wep = we + (d * C_ + c) * 9;
    float w9[9];
    #pragma unroll
    for (int i = 0; i < 9; i++) w9[i] = wep[i];

    __syncthreads();

    // erosion: e = -(1/b) logsumexp b*(w - x); outside image -> -BIG (pad for dilation)
    for (int idx = tid; idx < ET * ET; idx += 256) {
        int r = idx / ET, q = idx - r * ET;
        int gh = h0 - D + r, gw = w0 - D + q;
        float e;
        if (gh >= 0 && gh < H_ && gw >= 0 && gw < W_) {
            float u[9];
            #pragma unroll
            for (int i = 0; i < 3; i++)
                #pragma unroll
                for (int j = 0; j < 3; j++)
                    u[i * 3 + j] = KL2E * (w9[i * 3 + j] - xs[(r + i * D) * XT + (q + j * D)]);
            float m = u[0];
            #pragma unroll
            for (int i = 1; i < 9; i++) m = fmaxf(m, u[i]);
            float s = 0.f;
            #pragma unroll
            for (int i = 0; i < 9; i++) s += exp2f(u[i] - m);
            e = -C1 * (m + log2f(s));
        } else {
            e = -BIGV;
        }
        es[idx] = e;
    }

    const float* wdp = wd + (d * C_ + c) * 9;
    #pragma unroll
    for (int i = 0; i < 9; i++) w9[i] = wdp[i];
    const int bc = d * C_ + c;
    float scale = bng[bc] * rsqrtf(bnv[bc] + EPSV);
    float shift = bnb[bc] - bnm[bc] * scale;

    __syncthreads();

    // dilation: y = (1/b) logsumexp b*(w + e); then BN + ReLU
    float* catp = cat + ((size_t)(b * (4 * C_) + d * C_ + c)) * HW;
    for (int p = tid; p < 1024; p += 256) {
        int r = p >> 5, q = p & 31;
        float u[9];
        #pragma unroll
        for (int i = 0; i < 3; i++)
            #pragma unroll
            for (int j = 0; j < 3; j++)
                u[i * 3 + j] = KL2E * (w9[i * 3 + j] + es[(r + i * D) * ET + (q + j * D)]);
        float m = u[0];
        #pragma unroll
        for (int i = 1; i < 9; i++) m = fmaxf(m, u[i]);
        float s = 0.f;
        #pragma unroll
        for (int i = 0; i < 9; i++) s += exp2f(u[i] - m);
        float y = C1 * (m + log2f(s));
        y = fmaxf(0.f, y * scale + shift);
        catp[(h0 + r) * W_ + (w0 + q)] = y;
    }
}

// out[b,o,px] = relu(bn(sum_c W[o,c] * cat[b,c,px])), W is 64x256, K=256
__global__ __launch_bounds__(256) void conv_bn_relu_kernel(
    const float* __restrict__ cat, const float* __restrict__ cw,
    const float* __restrict__ g, const float* __restrict__ bb,
    const float* __restrict__ bm, const float* __restrict__ bv,
    float* __restrict__ out)
{
    __shared__ float ws[64 * 256];  // 64 KB: full weight matrix
    const int tid = threadIdx.x;
    for (int i = tid; i < 64 * 256; i += 256) ws[i] = cw[i];
    __syncthreads();

    const int tx = tid & 31, ty = tid >> 5;  // ty: 8 groups of 8 outputs
    const int b = blockIdx.y;
    const int px0 = blockIdx.x * 128;        // 128 pixels per block
    const float* catb = cat + (size_t)b * 256 * HW + px0 + tx;

    float acc[4][8];
    #pragma unroll
    for (int pp = 0; pp < 4; pp++)
        #pragma unroll
        for (int oo = 0; oo < 8; oo++) acc[pp][oo] = 0.f;

    for (int c = 0; c < 256; c += 4) {
        float cv[4][4];
        #pragma unroll
        for (int cc = 0; cc < 4; cc++)
            #pragma unroll
            for (int pp = 0; pp < 4; pp++)
                cv[cc][pp] = catb[(size_t)(c + cc) * HW + pp * 32];
        #pragma unroll
        for (int oo = 0; oo < 8; oo++) {
            const int o = ty * 8 + oo;
            const float4 wv = *(const float4*)&ws[o * 256 + c];
            #pragma unroll
            for (int pp = 0; pp < 4; pp++) {
                acc[pp][oo] = fmaf(wv.x, cv[0][pp], acc[pp][oo]);
                acc[pp][oo] = fmaf(wv.y, cv[1][pp], acc[pp][oo]);
                acc[pp][oo] = fmaf(wv.z, cv[2][pp], acc[pp][oo]);
                acc[pp][oo] = fmaf(wv.w, cv[3][pp], acc[pp][oo]);
            }
        }
    }

    #pragma unroll
    for (int oo = 0; oo < 8; oo++) {
        const int o = ty * 8 + oo;
        float scale = g[o] * rsqrtf(bv[o] + EPSV);
        float shift = bb[o] - bm[o] * scale;
        float* op = out + ((size_t)(b * 64 + o)) * HW + px0 + tx;
        #pragma unroll
        for (int pp = 0; pp < 4; pp++)
            op[pp * 32] = fmaxf(0.f, acc[pp][oo] * scale + shift);
    }
}

extern "C" void kernel_launch(void* const* d_in, const int* in_sizes, int n_in,
                              void* d_out, int out_size, void* d_ws, size_t ws_size,
                              hipStream_t stream)
{
    const float* x   = (const float*)d_in[0];
    const float* we  = (const float*)d_in[1];
    const float* wd  = (const float*)d_in[2];
    const float* bng = (const float*)d_in[3];
    const float* bnb = (const float*)d_in[4];
    const float* bnm = (const float*)d_in[5];
    const float* bnv = (const float*)d_in[6];
    const float* cw  = (const float*)d_in[7];
    const float* fg  = (const float*)d_in[8];
    const float* fb  = (const float*)d_in[9];
    const float* fm  = (const float*)d_in[10];
    const float* fv  = (const float*)d_in[11];
    float* out = (float*)d_out;
    float* cat = (float*)d_ws;  // needs 4*256*65536*4 B = 256 MiB scratch

    dim3 grid1(64, 64, 4);  // (8x8 tiles, C, B)
    morph_open_kernel<1><<<grid1, 256, 0, stream>>>(x, we, wd, bng, bnb, bnm, bnv, cat, 0);
    morph_open_kernel<2><<<grid1, 256, 0, stream>>>(x, we, wd, bng, bnb, bnm, bnv, cat, 1);
    morph_open_kernel<3><<<grid1, 256, 0, stream>>>(x, we, wd, bng, bnb, bnm, bnv, cat, 2);
    morph_open_kernel<4><<<grid1, 256, 0, stream>>>(x, we, wd, bng, bnb, bnm, bnv, cat, 3);

    conv_bn_relu_kernel<<<dim3(512, 4), 256, 0, stream>>>(cat, cw, fg, fb, fm, fv, out);
}

// Round 2
// 575.587 us; speedup vs baseline: 1.4317x; 1.4317x over previous
//
#include <hip/hip_runtime.h>
#include <hip/hip_fp16.h>
#include <math.h>

// MSMOM: multi-scale soft morphological opening + BN/ReLU + 1x1 conv + BN/ReLU
// B=4, C=64, H=W=256, k=3, dilations 1..4, beta=15.

constexpr int C_ = 64, H_ = 256, W_ = 256;
constexpr int HW = H_ * W_;
constexpr float BIGV = 10000.0f;
constexpr float EPSV = 1e-5f;
constexpr float KL2E = 21.64042561333445f;    // beta * log2(e)
constexpr float C1   = 0.046209812037329684f; // ln(2) / beta   (KL2E*C1 == 1)

// transposed conv weights: g_wT[c*64 + o] = conv_w[o*256 + c]  (c-major, wave-uniform reads)
__device__ __align__(256) float g_wT[256 * 64];

__global__ __launch_bounds__(256) void transpose_w(const float* __restrict__ cw) {
    int i = blockIdx.x * 256 + threadIdx.x;  // 16384 elems, grid=64
    int o = i >> 8, c = i & 255;
    g_wT[c * 64 + o] = cw[i];
}

// One block = one 32x32 tile of one (b,c); computes all 4 dilations reusing staged x.
// xs: x*KL2E with halo 8 (covers taps of all D<=4). es: erosion*KL2E, halo 4, fixed stride 40.
__global__ __launch_bounds__(256) void morph_all(
    const float* __restrict__ x, const float* __restrict__ we,
    const float* __restrict__ wd, const float* __restrict__ bng,
    const float* __restrict__ bnb, const float* __restrict__ bnm,
    const float* __restrict__ bnv, __half* __restrict__ cat)
{
    __shared__ float xs[48 * 48];
    __shared__ float es[40 * 40];
    const int tid = threadIdx.x, tx = tid & 31, ty = tid >> 5;
    const int tileW = blockIdx.x & 7, tileH = blockIdx.x >> 3;
    const int c = blockIdx.y, b = blockIdx.z;
    const int h0 = tileH * 32, w0 = tileW * 32;
    const float* xc = x + (b * C_ + c) * HW;

    // stage KL2E*x (pad -> KL2E*BIG: erosion taps w-BIG underflow to exact 0)
    for (int idx = tid; idx < 48 * 48; idx += 256) {
        int r = idx / 48, q = idx - r * 48;
        int gh = h0 - 8 + r, gw = w0 - 8 + q;
        float v = BIGV;
        if (gh >= 0 && gh < H_ && gw >= 0 && gw < W_) v = xc[gh * W_ + gw];
        xs[idx] = KL2E * v;
    }

    for (int d = 0; d < 4; d++) {
        const int D = d + 1, ET = 32 + 2 * D;
        const float* wep = we + (d * C_ + c) * 9;
        float wk[9];
        #pragma unroll
        for (int i = 0; i < 9; i++) wk[i] = KL2E * wep[i];

        __syncthreads();  // staging done (d=0) / previous dilation reads done (d>0)

        // erosion: es = KL2E*e = -(m + log2 sum 2^(u-m)),  u = wK - xK
        for (int r = ty; r < ET; r += 8) {
            for (int q = tx; q < ET; q += 32) {
                int gh = h0 - D + r, gw = w0 - D + q;
                float e;
                if (gh >= 0 && gh < H_ && gw >= 0 && gw < W_) {
                    float u[9];
                    #pragma unroll
                    for (int i = 0; i < 3; i++)
                        #pragma unroll
                        for (int j = 0; j < 3; j++)
                            u[i * 3 + j] = wk[i * 3 + j]
                                - xs[(r + 8 + (i - 2) * D) * 48 + (q + 8 + (j - 2) * D)];
                    float m = u[0];
                    #pragma unroll
                    for (int i = 1; i < 9; i++) m = fmaxf(m, u[i]);
                    float s = 0.f;
                    #pragma unroll
                    for (int i = 0; i < 9; i++) s += __builtin_amdgcn_exp2f(u[i] - m);
                    e = -m - __builtin_amdgcn_logf(s);
                } else {
                    e = -KL2E * BIGV;  // pad for dilation
                }
                es[(r + 4 - D) * 40 + (q + 4 - D)] = e;
            }
        }

        const float* wdp = wd + (d * C_ + c) * 9;
        #pragma unroll
        for (int i = 0; i < 9; i++) wk[i] = KL2E * wdp[i];
        const int bc = d * C_ + c;
        float scale = bng[bc] * rsqrtf(bnv[bc] + EPSV);
        float shift = bnb[bc] - bnm[bc] * scale;
        float cs = C1 * scale;

        __syncthreads();  // es ready

        // dilation: y = C1*(m + log2 sum), u = wK + es; then BN + ReLU, fp16 store
        __half* catp = cat + ((size_t)((b * 4 + d) * C_ + c)) * HW;
        #pragma unroll
        for (int k = 0; k < 4; k++) {
            int p = tid + k * 256;
            int r = p >> 5, q = p & 31;
            float u[9];
            #pragma unroll
            for (int i = 0; i < 3; i++)
                #pragma unroll
                for (int j = 0; j < 3; j++)
                    u[i * 3 + j] = wk[i * 3 + j]
                        + es[(r + 4 + (i - 1) * D) * 40 + (q + 4 + (j - 1) * D)];
            float m = u[0];
            #pragma unroll
            for (int i = 1; i < 9; i++) m = fmaxf(m, u[i]);
            float s = 0.f;
            #pragma unroll
            for (int i = 0; i < 9; i++) s += __builtin_amdgcn_exp2f(u[i] - m);
            float y = (m + __builtin_amdgcn_logf(s)) * cs + shift;
            catp[(h0 + r) * W_ + (w0 + q)] = __float2half(fmaxf(0.f, y));
        }
    }
}

// out[b,o,px] = relu(bn(sum_c W[o,c]*cat[b,c,px])). One thread = 1 pixel x 64 outputs.
// Weights read wave-uniformly from g_wT (c-major) -> scalar loads, no LDS.
__global__ __launch_bounds__(256) void conv_bn_relu(
    const __half* __restrict__ cat, const float* __restrict__ g,
    const float* __restrict__ bb, const float* __restrict__ bm,
    const float* __restrict__ bv, float* __restrict__ out)
{
    int gid = blockIdx.x * 256 + threadIdx.x;  // 262144 threads
    int b = gid >> 16, px = gid & 65535;
    const __half* cb = cat + (size_t)b * 256 * HW + px;

    float acc[64];
    #pragma unroll
    for (int o = 0; o < 64; o++) acc[o] = 0.f;

    for (int c = 0; c < 256; c += 4) {
        float cv0 = __half2float(cb[(size_t)(c + 0) * HW]);
        float cv1 = __half2float(cb[(size_t)(c + 1) * HW]);
        float cv2 = __half2float(cb[(size_t)(c + 2) * HW]);
        float cv3 = __half2float(cb[(size_t)(c + 3) * HW]);
        const float* w0 = &g_wT[c * 64];
        #pragma unroll
        for (int o = 0; o < 64; o++) {
            float a = acc[o];
            a = fmaf(w0[o],       cv0, a);
            a = fmaf(w0[64 + o],  cv1, a);
            a = fmaf(w0[128 + o], cv2, a);
            a = fmaf(w0[192 + o], cv3, a);
            acc[o] = a;
        }
    }

    float* ob = out + (size_t)b * 64 * HW + px;
    #pragma unroll
    for (int o = 0; o < 64; o++) {
        float scale = g[o] * rsqrtf(bv[o] + EPSV);
        float shift = bb[o] - bm[o] * scale;
        ob[(size_t)o * HW] = fmaxf(0.f, acc[o] * scale + shift);
    }
}

extern "C" void kernel_launch(void* const* d_in, const int* in_sizes, int n_in,
                              void* d_out, int out_size, void* d_ws, size_t ws_size,
                              hipStream_t stream)
{
    const float* x   = (const float*)d_in[0];
    const float* we  = (const float*)d_in[1];
    const float* wd  = (const float*)d_in[2];
    const float* bng = (const float*)d_in[3];
    const float* bnb = (const float*)d_in[4];
    const float* bnm = (const float*)d_in[5];
    const float* bnv = (const float*)d_in[6];
    const float* cw  = (const float*)d_in[7];
    const float* fg  = (const float*)d_in[8];
    const float* fb  = (const float*)d_in[9];
    const float* fm  = (const float*)d_in[10];
    const float* fv  = (const float*)d_in[11];
    float* out = (float*)d_out;
    __half* cat = (__half*)d_ws;  // 4*256*65536*2 B = 128 MiB

    transpose_w<<<64, 256, 0, stream>>>(cw);
    morph_all<<<dim3(64, 64, 4), 256, 0, stream>>>(x, we, wd, bng, bnb, bnm, bnv, cat);
    conv_bn_relu<<<1024, 256, 0, stream>>>(cat, fg, fb, fm, fv, out);
}

// Round 3
// 436.253 us; speedup vs baseline: 1.8890x; 1.3194x over previous
//
#include <hip/hip_runtime.h>
#include <hip/hip_fp16.h>
#include <math.h>

// MSMOM: multi-scale soft morphological opening + BN/ReLU + 1x1 conv + BN/ReLU
// B=4, C=64, H=W=256, k=3, dilations 1..4, beta=15.

constexpr int C_ = 64, H_ = 256, W_ = 256;
constexpr int HW = H_ * W_;
constexpr float BIGV = 10000.0f;
constexpr float EPSV = 1e-5f;
constexpr float KL2E = 21.64042561333445f;    // beta * log2(e)
constexpr float C1   = 0.046209812037329684f; // ln(2) / beta   (KL2E*C1 == 1)

typedef __attribute__((ext_vector_type(8))) _Float16 half8v;
typedef __attribute__((ext_vector_type(4))) _Float16 half4v;
typedef __attribute__((ext_vector_type(4))) float f32x4;

__device__ _Float16 g_wh[64 * 256];  // conv weights fp16, row-major [o][c]
__device__ float g_scale[64];
__device__ float g_shift[64];

__global__ __launch_bounds__(256) void prep(
    const float* __restrict__ cw, const float* __restrict__ g,
    const float* __restrict__ bb, const float* __restrict__ bm,
    const float* __restrict__ bv)
{
    int i = blockIdx.x * 256 + threadIdx.x;  // 16384 total
    g_wh[i] = (_Float16)cw[i];
    if (i < 64) {
        float s = g[i] * rsqrtf(bv[i] + EPSV);
        g_scale[i] = s;
        g_shift[i] = bb[i] - bm[i] * s;
    }
}

// One block = one 32x32 tile of one (b,c); all 4 dilations reuse staged x.
// xs: KL2E*x, 48x48 (halo 8). es: KL2E*erosion, 40x40 (halo 4), computed in full
// for every D (out-of-need cells are never read; indices stay branch-free).
// 4-px-per-lane groups: tap window for any D<=4 is exactly 3 aligned float4s
// starting at the group base ((q0+4-D)&~3 == q0 since 4-D in [0,3]).
__global__ __launch_bounds__(256) void morph_all(
    const float* __restrict__ x, const float* __restrict__ we,
    const float* __restrict__ wd, const float* __restrict__ bng,
    const float* __restrict__ bnb, const float* __restrict__ bnm,
    const float* __restrict__ bnv, _Float16* __restrict__ cat)
{
    __shared__ __align__(16) float xs[48 * 48];
    __shared__ __align__(16) float es[40 * 40];
    const int tid = threadIdx.x;
    const int tileW = blockIdx.x & 7, tileH = blockIdx.x >> 3;
    const int c = blockIdx.y, b = blockIdx.z;
    const int h0 = tileH * 32, w0 = tileW * 32;
    const float* xc = x + (b * C_ + c) * HW;

    const bool interior = (tileH != 0) & (tileH != 7) & (tileW != 0) & (tileW != 7);
    if (interior) {
        // guard-free vector staging (halo fully inside image)
        for (int u = tid; u < 576; u += 256) {
            int r = u / 12, q4 = (u - r * 12) * 4;
            const float4 v = *(const float4*)&xc[(h0 - 8 + r) * W_ + (w0 - 8 + q4)];
            float4 s;
            s.x = KL2E * v.x; s.y = KL2E * v.y; s.z = KL2E * v.z; s.w = KL2E * v.w;
            *(float4*)&xs[r * 48 + q4] = s;
        }
    } else {
        for (int u = tid; u < 2304; u += 256) {
            int r = u / 48, q = u - r * 48;
            int gh = h0 - 8 + r, gw = w0 - 8 + q;
            float v = BIGV;  // pad: erosion taps w - BIG underflow to exact 0
            if ((unsigned)gh < 256u && (unsigned)gw < 256u) v = xc[gh * W_ + gw];
            xs[u] = KL2E * v;
        }
    }

    const int dr = tid >> 3, dq0 = (tid & 7) * 4;  // dilation: 1 group/thread

    #pragma unroll
    for (int d = 0; d < 4; d++) {
        const int D = d + 1;
        float wk[9];
        const float* wep = we + (d * C_ + c) * 9;
        #pragma unroll
        for (int i = 0; i < 9; i++) wk[i] = KL2E * wep[i];

        __syncthreads();  // staging done / previous dilation reads done

        // erosion over full 40x40 es array, 400 groups of 4 px
        for (int g = tid; g < 400; g += 256) {
            int ra = g / 10, qa0 = (g - ra * 10) * 4;
            f32x4 xw[3][3];
            #pragma unroll
            for (int i = 0; i < 3; i++) {
                const f32x4* xr = (const f32x4*)&xs[(ra + 4 + (i - 1) * D) * 48 + qa0];
                xw[i][0] = xr[0]; xw[i][1] = xr[1]; xw[i][2] = xr[2];
            }
            const int gh = h0 + ra - 4;
            const bool rowok = (unsigned)gh < 256u;
            const int gw0 = w0 + qa0 - 4;
            f32x4 ev;
            #pragma unroll
            for (int p = 0; p < 4; p++) {
                float u[9];
                #pragma unroll
                for (int i = 0; i < 3; i++)
                    #pragma unroll
                    for (int j = 0; j < 3; j++) {
                        const int wi = (4 - D) + p + j * D;  // compile-time
                        u[i * 3 + j] = wk[i * 3 + j] - xw[i][wi >> 2][wi & 3];
                    }
                float m = u[0];
                #pragma unroll
                for (int i = 1; i < 9; i++) m = fmaxf(m, u[i]);
                float s = 0.f;
                #pragma unroll
                for (int i = 0; i < 9; i++) s += __builtin_amdgcn_exp2f(u[i] - m);
                float e = -m - __builtin_amdgcn_logf(s);
                bool ok = rowok && ((unsigned)(gw0 + p) < 256u);
                ev[p] = ok ? e : -KL2E * BIGV;  // pad for dilation
            }
            *(f32x4*)&es[ra * 40 + qa0] = ev;
        }

        float wdk[9];
        const float* wdp = wd + (d * C_ + c) * 9;
        #pragma unroll
        for (int i = 0; i < 9; i++) wdk[i] = KL2E * wdp[i];
        const int bc = d * C_ + c;
        float scale = bng[bc] * rsqrtf(bnv[bc] + EPSV);
        float shift = bnb[bc] - bnm[bc] * scale;
        float cs = C1 * scale;

        __syncthreads();  // es ready

        // dilation: 32x32 px, 256 groups of 4 px, + BN + ReLU, fp16 store
        {
            f32x4 ew[3][3];
            #pragma unroll
            for (int i = 0; i < 3; i++) {
                const f32x4* er = (const f32x4*)&es[(dr + 4 + (i - 1) * D) * 40 + dq0];
                ew[i][0] = er[0]; ew[i][1] = er[1]; ew[i][2] = er[2];
            }
            half4v hv;
            #pragma unroll
            for (int p = 0; p < 4; p++) {
                float u[9];
                #pragma unroll
                for (int i = 0; i < 3; i++)
                    #pragma unroll
                    for (int j = 0; j < 3; j++) {
                        const int wi = (4 - D) + p + j * D;
                        u[i * 3 + j] = wdk[i * 3 + j] + ew[i][wi >> 2][wi & 3];
                    }
                float m = u[0];
                #pragma unroll
                for (int i = 1; i < 9; i++) m = fmaxf(m, u[i]);
                float s = 0.f;
                #pragma unroll
                for (int i = 0; i < 9; i++) s += __builtin_amdgcn_exp2f(u[i] - m);
                float y = (m + __builtin_amdgcn_logf(s)) * cs + shift;
                hv[p] = (_Float16)fmaxf(0.f, y);
            }
            *(half4v*)&cat[((size_t)((b * 4 + d) * C_ + c)) * HW
                           + (h0 + dr) * W_ + (w0 + dq0)] = hv;
        }
    }
}

// Out[64 x 65536] = W[64x256] * Cat[256x65536] per batch, via mfma_f32_16x16x32_f16.
// A-frag: W row-major direct (lane m=o, 8 contiguous c). B-frag: 8 strided ushort
// gathers (lanes 0-15 px-contiguous -> 32B segments, cat is L3-resident). No LDS.
__global__ __launch_bounds__(256) void conv_mfma(
    const _Float16* __restrict__ cat, float* __restrict__ out)
{
    const int lane = threadIdx.x & 63, wave = threadIdx.x >> 6;
    const int m = lane & 15, quad = lane >> 4;
    const int b = blockIdx.y;
    const int px0 = blockIdx.x * 256 + wave * 64;  // 64 px per wave
    const _Float16* catb = cat + (size_t)b * 256 * HW;

    f32x4 acc[4][4];
    #pragma unroll
    for (int ot = 0; ot < 4; ot++)
        #pragma unroll
        for (int pt = 0; pt < 4; pt++)
            acc[ot][pt] = (f32x4){0.f, 0.f, 0.f, 0.f};

    #pragma unroll
    for (int kc = 0; kc < 8; kc++) {
        const int c0 = kc * 32 + quad * 8;
        half8v a0 = *(const half8v*)&g_wh[(0  + m) * 256 + c0];
        half8v a1 = *(const half8v*)&g_wh[(16 + m) * 256 + c0];
        half8v a2 = *(const half8v*)&g_wh[(32 + m) * 256 + c0];
        half8v a3 = *(const half8v*)&g_wh[(48 + m) * 256 + c0];
        #pragma unroll
        for (int pt = 0; pt < 4; pt++) {
            const int px = px0 + pt * 16 + m;
            half8v bf;
            #pragma unroll
            for (int j = 0; j < 8; j++)
                bf[j] = catb[(size_t)(c0 + j) * HW + px];
            acc[0][pt] = __builtin_amdgcn_mfma_f32_16x16x32_f16(a0, bf, acc[0][pt], 0, 0, 0);
            acc[1][pt] = __builtin_amdgcn_mfma_f32_16x16x32_f16(a1, bf, acc[1][pt], 0, 0, 0);
            acc[2][pt] = __builtin_amdgcn_mfma_f32_16x16x32_f16(a2, bf, acc[2][pt], 0, 0, 0);
            acc[3][pt] = __builtin_amdgcn_mfma_f32_16x16x32_f16(a3, bf, acc[3][pt], 0, 0, 0);
        }
    }

    // D layout: row(o) = quad*4 + reg, col(px) = m
    #pragma unroll
    for (int ot = 0; ot < 4; ot++)
        #pragma unroll
        for (int reg = 0; reg < 4; reg++) {
            const int o = ot * 16 + quad * 4 + reg;
            const float sc = g_scale[o], sh = g_shift[o];
            float* ob = out + ((size_t)(b * 64 + o)) * HW;
            #pragma unroll
            for (int pt = 0; pt < 4; pt++) {
                const int px = px0 + pt * 16 + m;
                ob[px] = fmaxf(0.f, acc[ot][pt][reg] * sc + sh);
            }
        }
}

extern "C" void kernel_launch(void* const* d_in, const int* in_sizes, int n_in,
                              void* d_out, int out_size, void* d_ws, size_t ws_size,
                              hipStream_t stream)
{
    const float* x   = (const float*)d_in[0];
    const float* we  = (const float*)d_in[1];
    const float* wd  = (const float*)d_in[2];
    const float* bng = (const float*)d_in[3];
    const float* bnb = (const float*)d_in[4];
    const float* bnm = (const float*)d_in[5];
    const float* bnv = (const float*)d_in[6];
    const float* cw  = (const float*)d_in[7];
    const float* fg  = (const float*)d_in[8];
    const float* fb  = (const float*)d_in[9];
    const float* fm  = (const float*)d_in[10];
    const float* fv  = (const float*)d_in[11];
    float* out = (float*)d_out;
    _Float16* cat = (_Float16*)d_ws;  // 4*256*65536*2 B = 128 MiB

    prep<<<64, 256, 0, stream>>>(cw, fg, fb, fm, fv);
    morph_all<<<dim3(64, 64, 4), 256, 0, stream>>>(x, we, wd, bng, bnb, bnm, bnv, cat);
    conv_mfma<<<dim3(256, 4), 256, 0, stream>>>(cat, out);
}

// Round 4
// 396.922 us; speedup vs baseline: 2.0761x; 1.0991x over previous
//
#include <hip/hip_runtime.h>
#include <hip/hip_fp16.h>
#include <math.h>

// MSMOM: multi-scale soft morphological opening + BN/ReLU + 1x1 conv + BN/ReLU
// B=4, C=64, H=W=256, k=3, dilations 1..4, beta=15.

constexpr int C_ = 64, H_ = 256, W_ = 256;
constexpr int HW = H_ * W_;
constexpr float BIGV = 10000.0f;
constexpr float EPSV = 1e-5f;
constexpr float KL2E = 21.64042561333445f;    // beta * log2(e)
constexpr float C1   = 0.046209812037329684f; // ln(2) / beta   (KL2E*C1 == 1)
constexpr float BIGK = KL2E * BIGV;

typedef __attribute__((ext_vector_type(8))) _Float16 half8v;
typedef __attribute__((ext_vector_type(4))) _Float16 half4v;
typedef __attribute__((ext_vector_type(4))) float f32x4;

__device__ _Float16 g_wh[64 * 256];  // conv weights fp16, row-major [o][c]
__device__ float g_scale[64];
__device__ float g_shift[64];

__global__ __launch_bounds__(256) void prep(
    const float* __restrict__ cw, const float* __restrict__ g,
    const float* __restrict__ bb, const float* __restrict__ bm,
    const float* __restrict__ bv)
{
    int i = blockIdx.x * 256 + threadIdx.x;  // 16384 total
    g_wh[i] = (_Float16)cw[i];
    if (i < 64) {
        float s = g[i] * rsqrtf(bv[i] + EPSV);
        g_scale[i] = s;
        g_shift[i] = bb[i] - bm[i] * s;
    }
}

// One block = one 64(h)x32(w) tile of one (b,c); all 4 dilations reuse staged x.
// xs: KL2E*x, 80x48 cells, stride 52 (pad: 52%32=20 breaks bank degeneracy).
// es: KL2E*erosion, 72 rows x 40 cols, stride 44 (44%32=12).
// 4-px groups: tap window for any D<=4 is 3 aligned f32x4 at the group base.
__global__ __launch_bounds__(256) void morph_all(
    const float* __restrict__ x, const float* __restrict__ we,
    const float* __restrict__ wd, const float* __restrict__ bng,
    const float* __restrict__ bnb, const float* __restrict__ bnm,
    const float* __restrict__ bnv, _Float16* __restrict__ cat)
{
    __shared__ __align__(16) float xs[80 * 52];
    __shared__ __align__(16) float es[72 * 44];
    const int tid = threadIdx.x;
    const int tileW = blockIdx.x & 7, tileH = blockIdx.x >> 3;  // 8 x 4 tiles
    const int c = blockIdx.y, b = blockIdx.z;
    const int h0 = tileH * 64, w0 = tileW * 32;
    const float* xc = x + (b * C_ + c) * HW;

    // unified branchless staging: clamped float4 load + group-level select
    // (gw is always a multiple of 4, so a group is entirely in or out by column)
    for (int u = tid; u < 960; u += 256) {   // 80 rows x 12 groups
        int r = u / 12, q4 = (u - r * 12) * 4;
        int gh = h0 - 8 + r, gw = w0 - 8 + q4;
        int ch = min(max(gh, 0), 255), cw = min(max(gw, 0), 252);
        const float4 v = *(const float4*)&xc[ch * W_ + cw];
        bool ok = ((unsigned)gh < 256u) && ((unsigned)gw < 253u);
        float4 sv;
        sv.x = ok ? KL2E * v.x : BIGK;
        sv.y = ok ? KL2E * v.y : BIGK;
        sv.z = ok ? KL2E * v.z : BIGK;
        sv.w = ok ? KL2E * v.w : BIGK;
        *(float4*)&xs[r * 52 + q4] = sv;
    }

    #pragma unroll
    for (int d = 0; d < 4; d++) {
        const int D = d + 1;
        float wk[9];
        const float* wep = we + (d * C_ + c) * 9;
        #pragma unroll
        for (int i = 0; i < 9; i++) wk[i] = KL2E * wep[i];

        __syncthreads();  // staging done / previous dilation reads of es done

        // erosion: only the (64+2D) rows needed, full 40-col width (10 groups)
        const int row0 = 4 - D, NG = (64 + 2 * D) * 10;
        for (int g = tid; g < NG; g += 256) {
            int ra = row0 + g / 10, qa0 = (g - (g / 10) * 10) * 4;
            f32x4 xw[3][3];
            #pragma unroll
            for (int i = 0; i < 3; i++) {
                const f32x4* xr = (const f32x4*)&xs[(ra + 4 + (i - 1) * D) * 52 + qa0];
                xw[i][0] = xr[0]; xw[i][1] = xr[1]; xw[i][2] = xr[2];
            }
            bool rowok = (unsigned)(h0 + ra - 4) < 256u;
            bool colok = (unsigned)(w0 + qa0 - 4) < 253u;
            bool ok = rowok && colok;
            f32x4 ev;
            #pragma unroll
            for (int p = 0; p < 4; p++) {
                float u[9];
                #pragma unroll
                for (int i = 0; i < 3; i++)
                    #pragma unroll
                    for (int j = 0; j < 3; j++) {
                        const int wi = (4 - D) + p + j * D;  // compile-time
                        u[i * 3 + j] = wk[i * 3 + j] - xw[i][wi >> 2][wi & 3];
                    }
                float m = fmaxf(fmaxf(fmaxf(u[0], u[1]), u[2]),
                                fmaxf(fmaxf(fmaxf(u[3], u[4]), u[5]),
                                      fmaxf(fmaxf(u[6], u[7]), u[8])));
                float s = 0.f;
                #pragma unroll
                for (int i = 0; i < 9; i++) s += __builtin_amdgcn_exp2f(u[i] - m);
                float e = -m - __builtin_amdgcn_logf(s);
                ev[p] = ok ? e : -BIGK;  // pad for dilation
            }
            *(f32x4*)&es[ra * 44 + qa0] = ev;
        }

        float wdk[9];
        const float* wdp = wd + (d * C_ + c) * 9;
        #pragma unroll
        for (int i = 0; i < 9; i++) wdk[i] = KL2E * wdp[i];
        const int bc = d * C_ + c;
        float scale = bng[bc] * rsqrtf(bnv[bc] + EPSV);
        float shift = bnb[bc] - bnm[bc] * scale;
        float cs = C1 * scale;

        __syncthreads();  // es ready

        // dilation: 64x32 px = 512 groups, 2 passes; + BN + ReLU, fp16 store
        _Float16* catp = cat + ((size_t)((b * 4 + d) * C_ + c)) * HW;
        #pragma unroll
        for (int pass = 0; pass < 2; pass++) {
            int gd = pass * 256 + tid;
            int dr = gd >> 3, dq0 = (gd & 7) * 4;
            f32x4 ew[3][3];
            #pragma unroll
            for (int i = 0; i < 3; i++) {
                const f32x4* er = (const f32x4*)&es[(dr + 4 + (i - 1) * D) * 44 + dq0];
                ew[i][0] = er[0]; ew[i][1] = er[1]; ew[i][2] = er[2];
            }
            half4v hv;
            #pragma unroll
            for (int p = 0; p < 4; p++) {
                float u[9];
                #pragma unroll
                for (int i = 0; i < 3; i++)
                    #pragma unroll
                    for (int j = 0; j < 3; j++) {
                        const int wi = (4 - D) + p + j * D;
                        u[i * 3 + j] = wdk[i * 3 + j] + ew[i][wi >> 2][wi & 3];
                    }
                float m = fmaxf(fmaxf(fmaxf(u[0], u[1]), u[2]),
                                fmaxf(fmaxf(fmaxf(u[3], u[4]), u[5]),
                                      fmaxf(fmaxf(u[6], u[7]), u[8])));
                float s = 0.f;
                #pragma unroll
                for (int i = 0; i < 9; i++) s += __builtin_amdgcn_exp2f(u[i] - m);
                float y = (m + __builtin_amdgcn_logf(s)) * cs + shift;
                hv[p] = (_Float16)fmaxf(0.f, y);
            }
            *(half4v*)&catp[(h0 + dr) * W_ + (w0 + dq0)] = hv;
        }
    }
}

// Out[64 x 65536] = W[64x256] * Cat[256x65536] per batch via mfma_f32_16x16x32_f16.
// cat chunk [32c x 256px] staged in LDS (stride 258 halves -> conflict-free
// ds_read_u16 B-frag gather: quads 8 banks apart, px pairs share a dword).
__global__ __launch_bounds__(256) void conv_mfma(
    const _Float16* __restrict__ cat, float* __restrict__ out)
{
    __shared__ _Float16 T[32 * 258];
    const int tid = threadIdx.x;
    const int lane = tid & 63, wave = tid >> 6;
    const int m = lane & 15, quad = lane >> 4;
    const int b = blockIdx.y;
    const int px0 = blockIdx.x * 256;
    const _Float16* catb = cat + (size_t)b * 256 * HW + px0;

    const int cl = tid >> 3;          // staged c row: 0..31
    const int px8 = (tid & 7) * 8;    // staged px base within 64-px pass

    f32x4 acc[4][4];
    #pragma unroll
    for (int ot = 0; ot < 4; ot++)
        #pragma unroll
        for (int pt = 0; pt < 4; pt++)
            acc[ot][pt] = (f32x4){0.f, 0.f, 0.f, 0.f};

    half8v sv[4];
    #pragma unroll
    for (int p = 0; p < 4; p++)
        sv[p] = *(const half8v*)&catb[(size_t)cl * HW + p * 64 + px8];

    for (int kc = 0; kc < 8; kc++) {
        const int c0 = kc * 32;
        __syncthreads();  // previous iteration's T reads done
        #pragma unroll
        for (int p = 0; p < 4; p++) {
            uint* tw = (uint*)&T[cl * 258 + p * 64 + px8];
            const uint* svw = (const uint*)&sv[p];
            tw[0] = svw[0]; tw[1] = svw[1]; tw[2] = svw[2]; tw[3] = svw[3];
        }
        __syncthreads();  // T ready

        if (kc < 7) {
            #pragma unroll
            for (int p = 0; p < 4; p++)
                sv[p] = *(const half8v*)&catb[(size_t)(c0 + 32 + cl) * HW + p * 64 + px8];
        }

        half8v a0 = *(const half8v*)&g_wh[(0  + m) * 256 + c0 + quad * 8];
        half8v a1 = *(const half8v*)&g_wh[(16 + m) * 256 + c0 + quad * 8];
        half8v a2 = *(const half8v*)&g_wh[(32 + m) * 256 + c0 + quad * 8];
        half8v a3 = *(const half8v*)&g_wh[(48 + m) * 256 + c0 + quad * 8];

        #pragma unroll
        for (int pt = 0; pt < 4; pt++) {
            const int pxl = wave * 64 + pt * 16 + m;
            const int tb = quad * 8 * 258 + pxl;
            half8v bf;
            #pragma unroll
            for (int j = 0; j < 8; j++)
                bf[j] = T[tb + j * 258];
            acc[0][pt] = __builtin_amdgcn_mfma_f32_16x16x32_f16(a0, bf, acc[0][pt], 0, 0, 0);
            acc[1][pt] = __builtin_amdgcn_mfma_f32_16x16x32_f16(a1, bf, acc[1][pt], 0, 0, 0);
            acc[2][pt] = __builtin_amdgcn_mfma_f32_16x16x32_f16(a2, bf, acc[2][pt], 0, 0, 0);
            acc[3][pt] = __builtin_amdgcn_mfma_f32_16x16x32_f16(a3, bf, acc[3][pt], 0, 0, 0);
        }
    }

    // D layout: row(o) = quad*4 + reg, col(px) = m
    #pragma unroll
    for (int ot = 0; ot < 4; ot++)
        #pragma unroll
        for (int reg = 0; reg < 4; reg++) {
            const int o = ot * 16 + quad * 4 + reg;
            const float sc = g_scale[o], sh = g_shift[o];
            float* ob = out + ((size_t)(b * 64 + o)) * HW + px0;
            #pragma unroll
            for (int pt = 0; pt < 4; pt++) {
                const int pxl = wave * 64 + pt * 16 + m;
                ob[pxl] = fmaxf(0.f, acc[ot][pt][reg] * sc + sh);
            }
        }
}

extern "C" void kernel_launch(void* const* d_in, const int* in_sizes, int n_in,
                              void* d_out, int out_size, void* d_ws, size_t ws_size,
                              hipStream_t stream)
{
    const float* x   = (const float*)d_in[0];
    const float* we  = (const float*)d_in[1];
    const float* wd  = (const float*)d_in[2];
    const float* bng = (const float*)d_in[3];
    const float* bnb = (const float*)d_in[4];
    const float* bnm = (const float*)d_in[5];
    const float* bnv = (const float*)d_in[6];
    const float* cw  = (const float*)d_in[7];
    const float* fg  = (const float*)d_in[8];
    const float* fb  = (const float*)d_in[9];
    const float* fm  = (const float*)d_in[10];
    const float* fv  = (const float*)d_in[11];
    float* out = (float*)d_out;
    _Float16* cat = (_Float16*)d_ws;  // 4*256*65536*2 B = 128 MiB

    prep<<<64, 256, 0, stream>>>(cw, fg, fb, fm, fv);
    morph_all<<<dim3(32, 64, 4), 256, 0, stream>>>(x, we, wd, bng, bnb, bnm, bnv, cat);
    conv_mfma<<<dim3(256, 4), 256, 0, stream>>>(cat, out);
}

// Round 5
// 263.234 us; speedup vs baseline: 3.1305x; 1.5079x over previous
//
#include <hip/hip_runtime.h>
#include <hip/hip_fp16.h>
#include <math.h>

// MSMOM: multi-scale soft morphological opening + BN/ReLU + 1x1 conv + BN/ReLU
// B=4, C=64, H=W=256, k=3, dilations 1..4, beta=15.
//
// Morph computed in exp2-domain: soft-ero/dil are linear correlations on
// P = 2^{-K x} (K = beta*log2e).  S1 = sum W*P  ->  2^{K e} = 1/S1 (rcp);
// dilation: out = C1*log2( sum Wd * (1/S1) ).  No per-pixel max needed:
// 2^{-Kx} spans 2^+-119 (x ~ N(0,1)) and 2^{Ke} spans ~2^[-108,43], both
// within fp32.  Flush-to-zero corner cases land on relu-0-correct outputs.

constexpr int C_ = 64, H_ = 256, W_ = 256;
constexpr int HW = H_ * W_;
constexpr float BIGV = 10000.0f;
constexpr float EPSV = 1e-5f;
constexpr float KL2E = 21.64042561333445f;    // beta * log2(e)
constexpr float C1   = 0.046209812037329684f; // ln(2) / beta

typedef __attribute__((ext_vector_type(8))) _Float16 half8v;
typedef __attribute__((ext_vector_type(4))) float f32x4;

__device__ _Float16 g_wh[64 * 256];  // conv weights fp16, row-major [o][c]
__device__ float g_scale[64];
__device__ float g_shift[64];

__global__ __launch_bounds__(256) void prep(
    const float* __restrict__ cw, const float* __restrict__ g,
    const float* __restrict__ bb, const float* __restrict__ bm,
    const float* __restrict__ bv)
{
    int i = blockIdx.x * 256 + threadIdx.x;  // 16384 total
    g_wh[i] = (_Float16)cw[i];
    if (i < 64) {
        float s = g[i] * rsqrtf(bv[i] + EPSV);
        g_scale[i] = s;
        g_shift[i] = bb[i] - bm[i] * s;
    }
}

// One block = one 64(h)x32(w) tile of one (b,c); all 4 dilations reuse staged P.
// xs: P = 2^{-K x}, 80 rows x 48 cols, stride 52.  es: Gw = 2^{K e}, 72 x 40,
// stride 44.  8-px groups: tap window for any D<=4 is 4 aligned f32x4.
__global__ __launch_bounds__(256) void morph_all(
    const float* __restrict__ x, const float* __restrict__ we,
    const float* __restrict__ wd, const float* __restrict__ bng,
    const float* __restrict__ bnb, const float* __restrict__ bnm,
    const float* __restrict__ bnv, _Float16* __restrict__ cat)
{
    __shared__ __align__(16) float xs[80 * 52];
    __shared__ __align__(16) float es[72 * 44];
    __shared__ float wsh[9], wdsh[9];
    const int tid = threadIdx.x;
    const int tileW = blockIdx.x & 7, tileH = blockIdx.x >> 3;  // 8 x 4 tiles
    const int c = blockIdx.y, b = blockIdx.z;
    const int h0 = tileH * 64, w0 = tileW * 32;
    const float* xc = x + (b * C_ + c) * HW;

    // staging: P = 2^{-K x}; out-of-image -> 0 (== 2^{-K*BIG} exactly)
    for (int u = tid; u < 960; u += 256) {   // 80 rows x 12 groups of 4
        int r = u / 12, q4 = (u - r * 12) * 4;
        int gh = h0 - 8 + r, gw = w0 - 8 + q4;
        int ch = min(max(gh, 0), 255), cwi = min(max(gw, 0), 252);
        const float4 v = *(const float4*)&xc[ch * W_ + cwi];
        bool ok = ((unsigned)gh < 256u) && ((unsigned)gw < 253u);
        float4 sv;
        sv.x = ok ? __builtin_amdgcn_exp2f(-KL2E * v.x) : 0.f;
        sv.y = ok ? __builtin_amdgcn_exp2f(-KL2E * v.y) : 0.f;
        sv.z = ok ? __builtin_amdgcn_exp2f(-KL2E * v.z) : 0.f;
        sv.w = ok ? __builtin_amdgcn_exp2f(-KL2E * v.w) : 0.f;
        *(float4*)&xs[r * 52 + q4] = sv;
    }

    #pragma unroll
    for (int d = 0; d < 4; d++) {
        const int D = d + 1;

        __syncthreads();  // staging / previous dilation reads done
        if (tid < 9)
            wsh[tid] = __builtin_amdgcn_exp2f(KL2E * we[(d * C_ + c) * 9 + tid]);
        else if (tid >= 16 && tid < 25)
            wdsh[tid - 16] = __builtin_amdgcn_exp2f(KL2E * wd[(d * C_ + c) * 9 + tid - 16]);
        __syncthreads();  // weights ready

        float w9[9];
        #pragma unroll
        for (int i = 0; i < 9; i++) w9[i] = wsh[i];

        // erosion: rows [4-D, 67+D], 5 groups of 8 px per row
        const int row0 = 4 - D, NG = (64 + 2 * D) * 5;
        for (int g = tid; g < NG; g += 256) {
            int gr = g / 5;
            int ra = row0 + gr, qa0 = (g - gr * 5) * 8;
            f32x4 xw[3][4];
            #pragma unroll
            for (int i = 0; i < 3; i++) {
                const f32x4* xr = (const f32x4*)&xs[(ra + 4 + (i - 1) * D) * 52 + qa0];
                xw[i][0] = xr[0]; xw[i][1] = xr[1]; xw[i][2] = xr[2]; xw[i][3] = xr[3];
            }
            bool rowok = (unsigned)(h0 + ra - 4) < 256u;
            const int gw0 = w0 + qa0 - 4;
            f32x4 gv[2];
            #pragma unroll
            for (int p = 0; p < 8; p++) {
                float s = 0.f;
                #pragma unroll
                for (int i = 0; i < 3; i++)
                    #pragma unroll
                    for (int j = 0; j < 3; j++) {
                        const int wi = (4 - D) + p + j * D;  // compile-time
                        s = fmaf(w9[i * 3 + j], xw[i][wi >> 2][wi & 3], s);
                    }
                float gwv = __builtin_amdgcn_rcpf(fmaxf(s, 1e-38f));
                bool ok = rowok && ((unsigned)(gw0 + p) < 256u);
                gv[p >> 2][p & 3] = ok ? gwv : 0.f;  // pad: 2^{K*(-BIG)} = 0
            }
            f32x4* ep = (f32x4*)&es[ra * 44 + qa0];
            ep[0] = gv[0]; ep[1] = gv[1];
        }

        float wd9[9];
        #pragma unroll
        for (int i = 0; i < 9; i++) wd9[i] = wdsh[i];
        const int bc = d * C_ + c;
        float scale = bng[bc] * rsqrtf(bnv[bc] + EPSV);
        float shift = bnb[bc] - bnm[bc] * scale;
        float cs = C1 * scale;

        __syncthreads();  // es ready

        // dilation: 64x32 px, one 8-px group per thread; BN + ReLU, fp16 store
        {
            const int dr = tid >> 2, dq0 = (tid & 3) * 8;
            f32x4 ew[3][4];
            #pragma unroll
            for (int i = 0; i < 3; i++) {
                const f32x4* er = (const f32x4*)&es[(dr + 4 + (i - 1) * D) * 44 + dq0];
                ew[i][0] = er[0]; ew[i][1] = er[1]; ew[i][2] = er[2]; ew[i][3] = er[3];
            }
            half8v hv;
            #pragma unroll
            for (int p = 0; p < 8; p++) {
                float s = 0.f;
                #pragma unroll
                for (int i = 0; i < 3; i++)
                    #pragma unroll
                    for (int j = 0; j < 3; j++) {
                        const int wi = (4 - D) + p + j * D;
                        s = fmaf(wd9[i * 3 + j], ew[i][wi >> 2][wi & 3], s);
                    }
                float y = __builtin_amdgcn_logf(fmaxf(s, 1e-38f)) * cs + shift;
                hv[p] = (_Float16)fmaxf(0.f, y);
            }
            *(half8v*)&cat[((size_t)((b * 4 + d) * C_ + c)) * HW
                           + (h0 + dr) * W_ + (w0 + dq0)] = hv;
        }
    }
}

// Out[64 x 65536] = W[64x256] * Cat[256x65536] per batch via mfma_f32_16x16x32_f16.
// Double-buffered LDS staging (1 sync/kc), prefetch depth 2.  T stride 258
// halves: B-frag ds_read_u16 quads land 8 banks apart, px pairs share a dword.
__global__ __launch_bounds__(256) void conv_mfma(
    const _Float16* __restrict__ cat, float* __restrict__ out)
{
    __shared__ _Float16 T[2][32 * 258];
    const int tid = threadIdx.x;
    const int lane = tid & 63, wave = tid >> 6;
    const int m = lane & 15, quad = lane >> 4;
    const int b = blockIdx.y;
    const int px0 = blockIdx.x * 256;
    const _Float16* catb = cat + (size_t)b * 256 * HW + px0;

    const int cl = tid >> 3;          // staged c row: 0..31
    const int px8 = (tid & 7) * 8;    // staged px base within 64-px strip

    f32x4 acc[4][4];
    #pragma unroll
    for (int ot = 0; ot < 4; ot++)
        #pragma unroll
        for (int pt = 0; pt < 4; pt++)
            acc[ot][pt] = (f32x4){0.f, 0.f, 0.f, 0.f};

    half8v sv[2][4];
    #pragma unroll
    for (int p = 0; p < 4; p++) {
        sv[0][p] = *(const half8v*)&catb[(size_t)cl * HW + p * 64 + px8];
        sv[1][p] = *(const half8v*)&catb[(size_t)(32 + cl) * HW + p * 64 + px8];
    }

    #pragma unroll
    for (int kc = 0; kc < 8; kc++) {
        const int buf = kc & 1;
        const int c0 = kc * 32;
        // write staged chunk (loaded 2 iterations ago)
        #pragma unroll
        for (int p = 0; p < 4; p++) {
            uint* tw = (uint*)&T[buf][cl * 258 + p * 64 + px8];
            const uint* svw = (const uint*)&sv[buf][p];
            tw[0] = svw[0]; tw[1] = svw[1]; tw[2] = svw[2]; tw[3] = svw[3];
        }
        // issue prefetch for kc+2
        if (kc < 6) {
            #pragma unroll
            for (int p = 0; p < 4; p++)
                sv[buf][p] = *(const half8v*)&catb[(size_t)(c0 + 64 + cl) * HW + p * 64 + px8];
        }
        __syncthreads();  // T[buf] ready (also separates from reads 2 iters ago)

        half8v a0 = *(const half8v*)&g_wh[(0  + m) * 256 + c0 + quad * 8];
        half8v a1 = *(const half8v*)&g_wh[(16 + m) * 256 + c0 + quad * 8];
        half8v a2 = *(const half8v*)&g_wh[(32 + m) * 256 + c0 + quad * 8];
        half8v a3 = *(const half8v*)&g_wh[(48 + m) * 256 + c0 + quad * 8];

        #pragma unroll
        for (int pt = 0; pt < 4; pt++) {
            const int pxl = wave * 64 + pt * 16 + m;
            const int tb = quad * 8 * 258 + pxl;
            half8v bf;
            #pragma unroll
            for (int j = 0; j < 8; j++)
                bf[j] = T[buf][tb + j * 258];
            acc[0][pt] = __builtin_amdgcn_mfma_f32_16x16x32_f16(a0, bf, acc[0][pt], 0, 0, 0);
            acc[1][pt] = __builtin_amdgcn_mfma_f32_16x16x32_f16(a1, bf, acc[1][pt], 0, 0, 0);
            acc[2][pt] = __builtin_amdgcn_mfma_f32_16x16x32_f16(a2, bf, acc[2][pt], 0, 0, 0);
            acc[3][pt] = __builtin_amdgcn_mfma_f32_16x16x32_f16(a3, bf, acc[3][pt], 0, 0, 0);
        }
    }

    // D layout: row(o) = quad*4 + reg, col(px) = m
    #pragma unroll
    for (int ot = 0; ot < 4; ot++)
        #pragma unroll
        for (int reg = 0; reg < 4; reg++) {
            const int o = ot * 16 + quad * 4 + reg;
            const float sc = g_scale[o], sh = g_shift[o];
            float* ob = out + ((size_t)(b * 64 + o)) * HW + px0;
            #pragma unroll
            for (int pt = 0; pt < 4; pt++) {
                const int pxl = wave * 64 + pt * 16 + m;
                ob[pxl] = fmaxf(0.f, acc[ot][pt][reg] * sc + sh);
            }
        }
}

extern "C" void kernel_launch(void* const* d_in, const int* in_sizes, int n_in,
                              void* d_out, int out_size, void* d_ws, size_t ws_size,
                              hipStream_t stream)
{
    const float* x   = (const float*)d_in[0];
    const float* we  = (const float*)d_in[1];
    const float* wd  = (const float*)d_in[2];
    const float* bng = (const float*)d_in[3];
    const float* bnb = (const float*)d_in[4];
    const float* bnm = (const float*)d_in[5];
    const float* bnv = (const float*)d_in[6];
    const float* cw  = (const float*)d_in[7];
    const float* fg  = (const float*)d_in[8];
    const float* fb  = (const float*)d_in[9];
    const float* fm  = (const float*)d_in[10];
    const float* fv  = (const float*)d_in[11];
    float* out = (float*)d_out;
    _Float16* cat = (_Float16*)d_ws;  // 4*256*65536*2 B = 128 MiB

    prep<<<64, 256, 0, stream>>>(cw, fg, fb, fm, fv);
    morph_all<<<dim3(32, 64, 4), 256, 0, stream>>>(x, we, wd, bng, bnb, bnm, bnv, cat);
    conv_mfma<<<dim3(256, 4), 256, 0, stream>>>(cat, out);
}

// Round 6
// 253.619 us; speedup vs baseline: 3.2492x; 1.0379x over previous
//
#include <hip/hip_runtime.h>
#include <hip/hip_fp16.h>
#include <math.h>

// MSMOM: multi-scale soft morphological opening + BN/ReLU + 1x1 conv + BN/ReLU
// B=4, C=64, H=W=256, k=3, dilations 1..4, beta=15.
//
// Morph computed in exp2-domain: soft-ero/dil are linear correlations on
// P = 2^{-K x} (K = beta*log2e).  S1 = sum W*P  ->  2^{K e} = 1/S1 (rcp);
// dilation: out = C1*log2( sum Wd * (1/S1) ).  No per-pixel max needed:
// 2^{-Kx} spans 2^+-119 (x ~ N(0,1)) and 2^{Ke} spans ~2^[-108,43], both
// within fp32.  Flush-to-zero corner cases land on relu-0-correct outputs.

constexpr int C_ = 64, H_ = 256, W_ = 256;
constexpr int HW = H_ * W_;
constexpr float EPSV = 1e-5f;
constexpr float KL2E = 21.64042561333445f;    // beta * log2(e)
constexpr float C1   = 0.046209812037329684f; // ln(2) / beta

typedef __attribute__((ext_vector_type(8))) _Float16 half8v;
typedef __attribute__((ext_vector_type(4))) float f32x4;

__device__ _Float16 g_wh[64 * 256];  // conv weights fp16, row-major [o][c]
__device__ float g_scale[64];
__device__ float g_shift[64];

__global__ __launch_bounds__(256) void prep(
    const float* __restrict__ cw, const float* __restrict__ g,
    const float* __restrict__ bb, const float* __restrict__ bm,
    const float* __restrict__ bv)
{
    int i = blockIdx.x * 256 + threadIdx.x;  // 16384 total
    g_wh[i] = (_Float16)cw[i];
    if (i < 64) {
        float s = g[i] * rsqrtf(bv[i] + EPSV);
        g_scale[i] = s;
        g_shift[i] = bb[i] - bm[i] * s;
    }
}

// One block = one 64x64 tile of one (b,c); all 4 dilations reuse staged P.
// xs: P = 2^{-K x}, 80 rows x 80 cols, stride 92 (28 mod 32 -> row bank
// offsets cycle uniformly over all 8 cosets).  es: 2^{K e}, 72 rows x 72
// cols (+pad), stride 84 (20 mod 32).  16-px-per-lane groups: tap window
// for any D<=4 is 6 aligned f32x4 at the group base ((4-D)+15+2D <= 23).
// Erosion is column-major (64 consecutive rows per wave -> bank-uniform);
// dilation is 16 rows x 4 col-groups (also bank-uniform).
__global__ __launch_bounds__(256) void morph_all(
    const float* __restrict__ x, const float* __restrict__ we,
    const float* __restrict__ wd, const float* __restrict__ bng,
    const float* __restrict__ bnb, const float* __restrict__ bnm,
    const float* __restrict__ bnv, _Float16* __restrict__ cat)
{
    __shared__ __align__(16) float xs[80 * 92];
    __shared__ __align__(16) float es[72 * 84];
    const int tid = threadIdx.x;
    const int tileW = blockIdx.x & 3, tileH = blockIdx.x >> 2;  // 4x4 tiles
    const int c = blockIdx.y, b = blockIdx.z;
    const int h0 = tileH * 64, w0 = tileW * 64;
    const float* xc = x + (b * C_ + c) * HW;

    // staging: P = 2^{-K x}; out-of-image -> 0 (== 2^{-K*BIG} exactly).
    // 80 rows x 20 float4-groups; group col-validity is all-or-nothing.
    for (int u = tid; u < 1600; u += 256) {
        int r = u / 20, q4 = (u - r * 20) * 4;
        int gh = h0 - 8 + r, gw = w0 - 8 + q4;
        int ch = min(max(gh, 0), 255), cwi = min(max(gw, 0), 252);
        const float4 v = *(const float4*)&xc[ch * W_ + cwi];
        bool ok = ((unsigned)gh < 256u) && ((unsigned)gw < 253u);
        float4 sv;
        sv.x = ok ? __builtin_amdgcn_exp2f(-KL2E * v.x) : 0.f;
        sv.y = ok ? __builtin_amdgcn_exp2f(-KL2E * v.y) : 0.f;
        sv.z = ok ? __builtin_amdgcn_exp2f(-KL2E * v.z) : 0.f;
        sv.w = ok ? __builtin_amdgcn_exp2f(-KL2E * v.w) : 0.f;
        *(float4*)&xs[r * 92 + q4] = sv;
    }

    #pragma unroll
    for (int d = 0; d < 4; d++) {
        const int D = d + 1;

        // weights: wave-uniform scalar loads (per-block c), exp2-domain
        float w9[9], wd9[9];
        #pragma unroll
        for (int i = 0; i < 9; i++) {
            w9[i]  = __builtin_amdgcn_exp2f(KL2E * we[(d * C_ + c) * 9 + i]);
            wd9[i] = __builtin_amdgcn_exp2f(KL2E * wd[(d * C_ + c) * 9 + i]);
        }
        const int bc = d * C_ + c;
        float scale = bng[bc] * rsqrtf(bnv[bc] + EPSV);
        float shift = bnb[bc] - bnm[bc] * scale;
        float cs = C1 * scale;

        __syncthreads();  // staging done / previous dilation reads of es done

        // erosion: 5 col-groups x 72 rows, column-major (bank-uniform).
        // es row a <-> image row h0-4+a <-> xs row a+4.
        for (int g = tid; g < 360; g += 256) {
            const int col = g / 72;            // wave-uniform-ish
            const int row = g - col * 72;
            const int qa0 = col * 16;
            float s16[16];
            #pragma unroll
            for (int p = 0; p < 16; p++) s16[p] = 0.f;
            #pragma unroll
            for (int i = 0; i < 3; i++) {
                const f32x4* xr = (const f32x4*)&xs[(row + 4 + (i - 1) * D) * 92 + qa0];
                f32x4 xw[6];
                #pragma unroll
                for (int k = 0; k < 6; k++) xw[k] = xr[k];
                #pragma unroll
                for (int j = 0; j < 3; j++) {
                    const float wv = w9[i * 3 + j];
                    #pragma unroll
                    for (int p = 0; p < 16; p++) {
                        const int wi = (4 - D) + p + j * D;  // compile-time
                        s16[p] = fmaf(wv, xw[wi >> 2][wi & 3], s16[p]);
                    }
                }
            }
            const bool rowok = (unsigned)(h0 + row - 4) < 256u;
            const int gw0 = w0 + qa0 - 4;
            f32x4 ev[4];
            #pragma unroll
            for (int p = 0; p < 16; p++) {
                float gv = __builtin_amdgcn_rcpf(fmaxf(s16[p], 1e-38f));
                bool ok = rowok && ((unsigned)(gw0 + p) < 256u);
                ev[p >> 2][p & 3] = ok ? gv : 0.f;  // pad: 2^{K*(-BIG)} = 0
            }
            f32x4* ep = (f32x4*)&es[row * 84 + qa0];  // cols 72..83 are pad
            ep[0] = ev[0]; ep[1] = ev[1]; ep[2] = ev[2]; ep[3] = ev[3];
        }

        __syncthreads();  // es ready

        // dilation: 64 rows x 4 col-groups of 16 px, one group per thread
        {
            const int dr = tid >> 2, dq0 = (tid & 3) * 16;
            float s16[16];
            #pragma unroll
            for (int p = 0; p < 16; p++) s16[p] = 0.f;
            #pragma unroll
            for (int i = 0; i < 3; i++) {
                const f32x4* er = (const f32x4*)&es[(dr + 4 + (i - 1) * D) * 84 + dq0];
                f32x4 ew[6];
                #pragma unroll
                for (int k = 0; k < 6; k++) ew[k] = er[k];
                #pragma unroll
                for (int j = 0; j < 3; j++) {
                    const float wv = wd9[i * 3 + j];
                    #pragma unroll
                    for (int p = 0; p < 16; p++) {
                        const int wi = (4 - D) + p + j * D;
                        s16[p] = fmaf(wv, ew[wi >> 2][wi & 3], s16[p]);
                    }
                }
            }
            half8v hv0, hv1;
            #pragma unroll
            for (int p = 0; p < 16; p++) {
                float y = __builtin_amdgcn_logf(fmaxf(s16[p], 1e-38f)) * cs + shift;
                y = fmaxf(0.f, y);
                if (p < 8) hv0[p] = (_Float16)y; else hv1[p - 8] = (_Float16)y;
            }
            _Float16* cp = &cat[((size_t)((b * 4 + d) * C_ + c)) * HW
                                + (h0 + dr) * W_ + (w0 + dq0)];
            *(half8v*)cp = hv0;
            *(half8v*)(cp + 8) = hv1;
        }
    }
}

// Out[64 x 65536] = W[64x256] * Cat[256x65536] per batch via mfma_f32_16x16x32_f16.
// Double-buffered LDS staging (1 sync/kc), prefetch depth 2.  T stride 258
// halves: B-frag ds_read_u16 quads land 8 banks apart, px pairs share a dword.
__global__ __launch_bounds__(256) void conv_mfma(
    const _Float16* __restrict__ cat, float* __restrict__ out)
{
    __shared__ _Float16 T[2][32 * 258];
    const int tid = threadIdx.x;
    const int lane = tid & 63, wave = tid >> 6;
    const int m = lane & 15, quad = lane >> 4;
    const int b = blockIdx.y;
    const int px0 = blockIdx.x * 256;
    const _Float16* catb = cat + (size_t)b * 256 * HW + px0;

    const int cl = tid >> 3;          // staged c row: 0..31
    const int px8 = (tid & 7) * 8;    // staged px base within 64-px strip

    f32x4 acc[4][4];
    #pragma unroll
    for (int ot = 0; ot < 4; ot++)
        #pragma unroll
        for (int pt = 0; pt < 4; pt++)
            acc[ot][pt] = (f32x4){0.f, 0.f, 0.f, 0.f};

    half8v sv[2][4];
    #pragma unroll
    for (int p = 0; p < 4; p++) {
        sv[0][p] = *(const half8v*)&catb[(size_t)cl * HW + p * 64 + px8];
        sv[1][p] = *(const half8v*)&catb[(size_t)(32 + cl) * HW + p * 64 + px8];
    }

    #pragma unroll
    for (int kc = 0; kc < 8; kc++) {
        const int buf = kc & 1;
        const int c0 = kc * 32;
        // write staged chunk (loaded 2 iterations ago)
        #pragma unroll
        for (int p = 0; p < 4; p++) {
            uint* tw = (uint*)&T[buf][cl * 258 + p * 64 + px8];
            const uint* svw = (const uint*)&sv[buf][p];
            tw[0] = svw[0]; tw[1] = svw[1]; tw[2] = svw[2]; tw[3] = svw[3];
        }
        // issue prefetch for kc+2
        if (kc < 6) {
            #pragma unroll
            for (int p = 0; p < 4; p++)
                sv[buf][p] = *(const half8v*)&catb[(size_t)(c0 + 64 + cl) * HW + p * 64 + px8];
        }
        __syncthreads();  // T[buf] ready

        half8v a0 = *(const half8v*)&g_wh[(0  + m) * 256 + c0 + quad * 8];
        half8v a1 = *(const half8v*)&g_wh[(16 + m) * 256 + c0 + quad * 8];
        half8v a2 = *(const half8v*)&g_wh[(32 + m) * 256 + c0 + quad * 8];
        half8v a3 = *(const half8v*)&g_wh[(48 + m) * 256 + c0 + quad * 8];

        #pragma unroll
        for (int pt = 0; pt < 4; pt++) {
            const int pxl = wave * 64 + pt * 16 + m;
            const int tb = quad * 8 * 258 + pxl;
            half8v bf;
            #pragma unroll
            for (int j = 0; j < 8; j++)
                bf[j] = T[buf][tb + j * 258];
            acc[0][pt] = __builtin_amdgcn_mfma_f32_16x16x32_f16(a0, bf, acc[0][pt], 0, 0, 0);
            acc[1][pt] = __builtin_amdgcn_mfma_f32_16x16x32_f16(a1, bf, acc[1][pt], 0, 0, 0);
            acc[2][pt] = __builtin_amdgcn_mfma_f32_16x16x32_f16(a2, bf, acc[2][pt], 0, 0, 0);
            acc[3][pt] = __builtin_amdgcn_mfma_f32_16x16x32_f16(a3, bf, acc[3][pt], 0, 0, 0);
        }
    }

    // D layout: row(o) = quad*4 + reg, col(px) = m
    #pragma unroll
    for (int ot = 0; ot < 4; ot++)
        #pragma unroll
        for (int reg = 0; reg < 4; reg++) {
            const int o = ot * 16 + quad * 4 + reg;
            const float sc = g_scale[o], sh = g_shift[o];
            float* ob = out + ((size_t)(b * 64 + o)) * HW + px0;
            #pragma unroll
            for (int pt = 0; pt < 4; pt++) {
                const int pxl = wave * 64 + pt * 16 + m;
                ob[pxl] = fmaxf(0.f, acc[ot][pt][reg] * sc + sh);
            }
        }
}

extern "C" void kernel_launch(void* const* d_in, const int* in_sizes, int n_in,
                              void* d_out, int out_size, void* d_ws, size_t ws_size,
                              hipStream_t stream)
{
    const float* x   = (const float*)d_in[0];
    const float* we  = (const float*)d_in[1];
    const float* wd  = (const float*)d_in[2];
    const float* bng = (const float*)d_in[3];
    const float* bnb = (const float*)d_in[4];
    const float* bnm = (const float*)d_in[5];
    const float* bnv = (const float*)d_in[6];
    const float* cw  = (const float*)d_in[7];
    const float* fg  = (const float*)d_in[8];
    const float* fb  = (const float*)d_in[9];
    const float* fm  = (const float*)d_in[10];
    const float* fv  = (const float*)d_in[11];
    float* out = (float*)d_out;
    _Float16* cat = (_Float16*)d_ws;  // 4*256*65536*2 B = 128 MiB

    prep<<<64, 256, 0, stream>>>(cw, fg, fb, fm, fv);
    morph_all<<<dim3(16, 64, 4), 256, 0, stream>>>(x, we, wd, bng, bnb, bnm, bnv, cat);
    conv_mfma<<<dim3(256, 4), 256, 0, stream>>>(cat, out);
}